// Round 6
// baseline (240.323 us; speedup 1.0000x reference)
//
#include <hip/hip_runtime.h>
#include <stdint.h>

#define D_DIM 784
#define H_DIM 1024
#define B_DIM 256
#define NBIN  10
#define G_CH  16            // i's per main block -> full 64B out lines
#define T_CH  49            // D_DIM / G_CH (main-block chunks)
#define P_CH  8             // i's per PA checkpoint
#define T_PS  98            // D_DIM / P_CH  (checkpoint count)
#define BT    16            // batch tile per main block (fixed by MFMA M=16)
#define LOG2E 1.4426950408889634f

#define VPREP_BLKS D_DIM    // 784
#define WPREP_BLKS 208      // 13 * 16 tiles of W transpose

typedef _Float16 half8_t  __attribute__((ext_vector_type(8)));
typedef __fp16   fp16x2_t __attribute__((ext_vector_type(2)));
typedef float    float4_t __attribute__((ext_vector_type(4)));

// ---------------------------------------------------------------------------
// k_prep: V -> VB MFMA-fragment reshape (blocks [0,784)) and
//         W -> Wt2h f16 transpose x LOG2E (blocks [784,992)). (unchanged)
// ---------------------------------------------------------------------------
__global__ void k_prep(const float* __restrict__ W, const float* __restrict__ V,
                       _Float16* __restrict__ Wt2h, _Float16* __restrict__ VB) {
    __shared__ __align__(16) float smem[5120];   // 20 KB
    int tid = threadIdx.x;
    int bx  = blockIdx.x;

    if (bx < VPREP_BLKS) {
        int i = bx;
        const float4* src = (const float4*)(V + (size_t)i * H_DIM * NBIN);
        uint4* dst = (uint4*)VB + (size_t)i * 2048;
        #pragma unroll
        for (int p = 0; p < 2; ++p) {
            if (p) __syncthreads();
            #pragma unroll
            for (int qv = 0; qv < 5; ++qv) {
                float4 v = src[p * 1280 + qv * 256 + tid];
                *((float4*)&smem[(qv * 256 + tid) * 4]) = v;
            }
            __syncthreads();
            #pragma unroll
            for (int qv = 0; qv < 4; ++qv) {
                int pair = p * 1024 + qv * 256 + tid;
                int kk = pair >> 6, ll = pair & 63;
                int n = ll & 15, hb = kk * 32 + ((ll >> 4) & 3) * 8;
                union { _Float16 hh[8]; uint4 u; } o;
                #pragma unroll
                for (int jj = 0; jj < 8; ++jj)
                    o.hh[jj] = (_Float16)((n < NBIN) ? smem[(hb + jj) * NBIN + n - p * 5120] : 0.0f);
                dst[pair] = o.u;
            }
        }
    } else {
        int qw = bx - VPREP_BLKS;
        int j0 = (qw % 13) * 64, h0 = (qw / 13) * 64;
        float (*t)[65] = (float(*)[65])smem;
        int tj = tid & 63, tr = tid >> 6;
        int j = j0 + tj;
        #pragma unroll
        for (int r = 0; r < 16; ++r) {
            int hh = tr * 16 + r;
            t[hh][tj] = (j < D_DIM) ? W[(size_t)(h0 + hh) * D_DIM + j] : 0.0f;
        }
        __syncthreads();
        #pragma unroll
        for (int r = 0; r < 16; ++r) {
            int jj = tr * 16 + r;
            int jo = j0 + jj;
            if (jo < D_DIM) Wt2h[(size_t)jo * H_DIM + h0 + tj] = (_Float16)(t[tj][jj] * LOG2E);
        }
    }
}

// ---------------------------------------------------------------------------
// k_pscan: coalesced prefix-scan, checkpoint every 8 i's (T_PS=98).
// Thread owns 2 adjacent h (one uint column); distance-1 register prefetch.
// ---------------------------------------------------------------------------
__global__ __launch_bounds__(256)
void k_pscan(const _Float16* __restrict__ Wt2h, const int* __restrict__ x,
             const float* __restrict__ c, _Float16* __restrict__ PA) {
    int b   = blockIdx.x;
    int hg  = blockIdx.y;
    int tid = threadIdx.x;
    int hcol = hg * 256 + tid;        // uint column 0..511
    int h0   = hcol * 2;

    __shared__ float xs[D_DIM];
    if (tid < D_DIM / 4) {
        int4 xi = ((const int4*)(x + (size_t)b * D_DIM))[tid];
        *((float4*)&xs[tid * 4]) =
            make_float4((float)xi.x, (float)xi.y, (float)xi.z, (float)xi.w);
    }
    float acc0 = c[h0] * LOG2E, acc1 = c[h0 + 1] * LOG2E;
    __syncthreads();

    const uint* wp  = (const uint*)Wt2h;   // [784][512] uints, h-contiguous
    uint*       pau = (uint*)PA;

    uint wvA[8], wvB[8];
    auto ldrow = [&](int t, uint (&wv)[8]) {
        #pragma unroll
        for (int r = 0; r < 8; ++r)
            wv[r] = wp[(size_t)(t * 8 + r) * 512 + hcol];
    };
    auto emit = [&](int t) {
        union { _Float16 hh[2]; uint u; } uu;
        uu.hh[0] = (_Float16)acc0; uu.hh[1] = (_Float16)acc1;
        pau[((size_t)t * B_DIM + b) * 512 + hcol] = uu.u;
    };
    auto fmas = [&](int t, const uint (&wv)[8]) {
        #pragma unroll
        for (int r = 0; r < 8; ++r) {
            union { uint u; _Float16 hh[2]; } uu; uu.u = wv[r];
            float xf = xs[t * 8 + r];
            acc0 += xf * (float)uu.hh[0];
            acc1 += xf * (float)uu.hh[1];
        }
    };

    ldrow(0, wvA);
    for (int t = 0; t < T_PS; t += 2) {       // t = 0,2,...,96
        ldrow(t + 1, wvB);
        emit(t);     fmas(t, wvA);
        if (t + 2 < T_PS) ldrow(t + 2, wvA);
        emit(t + 1); fmas(t + 1, wvB);
    }
}

// ---------------------------------------------------------------------------
// k_main: 512 threads = 2 groups x 4 waves. Group g owns i's [i0+8g, i0+8g+8)
// from its own PA checkpoint (stride-8 checkpoints). Block footprint stays
// 16 i's -> full 64B out lines (write-amp fix kept). Per-wave serial chain
// halves vs round 5; residency doubles (16 waves/CU @ launch_bounds(512,4)).
// ---------------------------------------------------------------------------
__global__ __launch_bounds__(512, 4)
void k_main(const _Float16* __restrict__ VB, const _Float16* __restrict__ Wt2h,
            const _Float16* __restrict__ PA, const int* __restrict__ x,
            const float* __restrict__ bias, float* __restrict__ out) {
    int bid = blockIdx.x;
    int lb  = (bid & 7) * 98 + (bid >> 3);   // XCD-chunked swizzle (784 = 8*98)
    int tc  = lb >> 4;           // chunk 0..48
    int bt  = lb & 15;           // batch tile 0..15
    int tid = threadIdx.x;
    int g   = tid >> 8;          // i-group 0/1
    int w   = (tid >> 6) & 3;    // wave within group (K-split of H)
    int l   = tid & 63;
    int bl  = l & 15;            // MFMA A row == batch row within tile
    int kg  = l >> 4;            // 0..3
    int bg  = bt * BT + bl;
    int ib  = tc * G_CH;         // block's first i
    int i0  = ib + g * P_CH;     // group's first i

    __shared__ float red[2][4][64][17];      // [group][wave][lane][16+pad] = 34.8 KB
    __shared__ float bs[G_CH][16];           // 1 KB

    {   // stage bias for the block's 16 i's (covered by barrier B1)
        if (tid < 256) {
            int ii = tid >> 4, n = tid & 15;
            bs[ii][n] = (n < NBIN) ? bias[(size_t)(ib + ii) * NBIN + n] : 0.0f;
        }
    }

    // a[8][8] from this group's PA checkpoint (exclusive prefix, log2 domain)
    float a[8][8];
    {
        int ct = tc * 2 + g;     // checkpoint index (stride-8)
        const _Float16* src = PA + ((size_t)ct * B_DIM + bg) * H_DIM + w * 256 + kg * 8;
        #pragma unroll
        for (int m = 0; m < 8; ++m) {
            half8_t av = *((const half8_t*)(src + m * 32));
            #pragma unroll
            for (int j = 0; j < 8; ++j) a[m][j] = (float)av[j];
        }
    }

    const int4* xp = (const int4*)(x + (size_t)bg * D_DIM + i0);

    // VB: 4-slot rolling prefetch over this group's 64 steps (8 ii x 8 m)
    const uint4* vp = (const uint4*)VB + ((size_t)i0 * 32 + w * 8) * 64 + l;
    uint4 vbuf[4];
    vbuf[0] = vp[0];
    vbuf[1] = vp[64];
    const uint4* vpr = vp + 128;             // next refill: step 2

    // Wt2h operand: 2-slot consume-then-refill (distance 2)
    const _Float16* whp = Wt2h + (size_t)i0 * H_DIM + w * 256 + kg * 8;
    half8_t whbuf[2];
    whbuf[0] = *((const half8_t*)whp);
    whbuf[1] = *((const half8_t*)(whp + 32));
    const _Float16* whr = whp + 64;          // next refill: step 2

    float4_t acc = {0.f, 0.f, 0.f, 0.f};

    auto softmax_store = [&](int q) {
        float p4[4];
        #pragma unroll
        for (int qq = 0; qq < 4; ++qq) {
            float tot = red[g][0][l][qq * 4 + w] + red[g][1][l][qq * 4 + w]
                      + red[g][2][l][qq * 4 + w] + red[g][3][l][qq * 4 + w];
            float v = (bl < NBIN) ? tot + bs[g * P_CH + q * 4 + qq][bl] : -3.0e38f;
            float vm = v;
            vm = fmaxf(vm, __shfl_xor(vm, 1));
            vm = fmaxf(vm, __shfl_xor(vm, 2));
            vm = fmaxf(vm, __shfl_xor(vm, 4));
            vm = fmaxf(vm, __shfl_xor(vm, 8));
            float e = __builtin_amdgcn_exp2f((v - vm) * LOG2E);
            float ss = e;
            ss += __shfl_xor(ss, 1); ss += __shfl_xor(ss, 2);
            ss += __shfl_xor(ss, 4); ss += __shfl_xor(ss, 8);
            p4[qq] = e * __builtin_amdgcn_rcpf(ss);
        }
        if (bl < NBIN) {
            int b = bt * BT + kg * 4 + w;    // this thread's C row = batch row
            size_t base = ((size_t)b * NBIN + bl) * D_DIM + i0 + q * 4;
            *((float4*)(out + base)) = make_float4(p4[0], p4[1], p4[2], p4[3]);
        }
    };

    for (int q = 0; q < 2; ++q) {            // two quarters of 4 i's per group
        int4 xi = xp[q];
        float xq0 = (float)xi.x, xq1 = (float)xi.y, xq2 = (float)xi.z, xq3 = (float)xi.w;
        #pragma unroll
        for (int s = 0; s < 32; ++s) {       // all register indices static in s
            const int iis = s >> 3;          // ii within quarter
            const int m   = s & 7;
            const int nn  = q * 32 + s + 2;  // prefetch target (of 64)
            half8_t wh = whbuf[s & 1];       // consume ...
            if (nn < 64) {                   // ... then refill same slot for s+2
                vbuf[(s + 2) & 3] = *vpr;
                whbuf[s & 1] = *((const half8_t*)whr);
                vpr += (((s + 3) & 7) == 0) ? 1600 : 64;   // uint4 stride to nn+1
                whr += (((s + 3) & 7) == 0) ? 800  : 32;   // f16 stride to nn+1
            }
            union { half8_t h8; uint u32[4]; } af;
            #pragma unroll
            for (int p = 0; p < 4; ++p) {
                float s0 = __builtin_amdgcn_rcpf(1.0f + __builtin_amdgcn_exp2f(-a[m][2 * p]));
                float s1 = __builtin_amdgcn_rcpf(1.0f + __builtin_amdgcn_exp2f(-a[m][2 * p + 1]));
                union { fp16x2_t v; uint u; } cv;
                cv.v = __builtin_amdgcn_cvt_pkrtz(s0, s1);
                af.u32[p] = cv.u;
            }
            union { half8_t h8; uint4 u; } bf;
            bf.u = vbuf[s & 3];
            acc = __builtin_amdgcn_mfma_f32_16x16x32_f16(af.h8, bf.h8, acc, 0, 0, 0);
            float xf = (iis == 0) ? xq0 : (iis == 1) ? xq1 : (iis == 2) ? xq2 : xq3;
            a[m][0] += xf * (float)wh[0]; a[m][1] += xf * (float)wh[1];
            a[m][2] += xf * (float)wh[2]; a[m][3] += xf * (float)wh[3];
            a[m][4] += xf * (float)wh[4]; a[m][5] += xf * (float)wh[5];
            a[m][6] += xf * (float)wh[6]; a[m][7] += xf * (float)wh[7];
            if (m == 7) {                    // flush this ii's logits
                float* rp = &red[g][w][l][iis * 4];
                rp[0] = acc[0]; rp[1] = acc[1]; rp[2] = acc[2]; rp[3] = acc[3];
                acc = (float4_t){0.f, 0.f, 0.f, 0.f};
            }
        }
        __syncthreads();                     // red[g] complete (q=0 also covers bs)
        softmax_store(q);
        if (q == 0) __syncthreads();         // all softmax reads done before Q1 flush
    }
}

extern "C" void kernel_launch(void* const* d_in, const int* in_sizes, int n_in,
                              void* d_out, int out_size, void* d_ws, size_t ws_size,
                              hipStream_t stream) {
    const int*   x    = (const int*)d_in[0];
    const float* W    = (const float*)d_in[1];
    const float* c    = (const float*)d_in[2];
    const float* V    = (const float*)d_in[3];
    const float* bias = (const float*)d_in[4];
    float* out = (float*)d_out;

    char* ws = (char*)d_ws;
    size_t off = 0;
    _Float16* Wt2h = (_Float16*)(ws + off);
    off += (size_t)D_DIM * H_DIM * sizeof(_Float16);
    off = (off + 255) & ~(size_t)255;
    _Float16* VB = (_Float16*)(ws + off);
    off += (size_t)D_DIM * 32 * 64 * 8 * sizeof(_Float16);
    off = (off + 255) & ~(size_t)255;
    _Float16* PA = (_Float16*)(ws + off);   // [98][256][1024] f16 = 51.4 MB

    k_prep<<<dim3(VPREP_BLKS + WPREP_BLKS), 256, 0, stream>>>(W, V, Wt2h, VB);
    k_pscan<<<dim3(B_DIM, 2), 256, 0, stream>>>(Wt2h, x, c, PA);
    k_main<<<dim3(D_DIM), 512, 0, stream>>>(VB, Wt2h, PA, x, bias, out);
}

// Round 7
// 200.639 us; speedup vs baseline: 1.1978x; 1.1978x over previous
//
#include <hip/hip_runtime.h>
#include <stdint.h>

#define D_DIM 784
#define H_DIM 1024
#define B_DIM 256
#define NBIN  10
#define G_CH  16            // i's per main block -> full 64B out lines
#define T_CH  49            // D_DIM / G_CH (main-block chunks)
#define P_CH  8             // i's per PA checkpoint
#define T_PS  98            // D_DIM / P_CH  (checkpoint count)
#define BT    16            // batch tile per main block (fixed by MFMA M=16)
#define LOG2E 1.4426950408889634f

#define VPREP_BLKS D_DIM    // 784
#define WPREP_BLKS 208      // 13 * 16 tiles of W transpose

typedef _Float16 half8_t  __attribute__((ext_vector_type(8)));
typedef __fp16   fp16x2_t __attribute__((ext_vector_type(2)));
typedef float    float4_t __attribute__((ext_vector_type(4)));

// ---------------------------------------------------------------------------
// k_prep: V -> VB MFMA-fragment reshape (blocks [0,784)) and
//         W -> Wt2h f16 transpose x LOG2E (blocks [784,992)). (unchanged)
// ---------------------------------------------------------------------------
__global__ void k_prep(const float* __restrict__ W, const float* __restrict__ V,
                       _Float16* __restrict__ Wt2h, _Float16* __restrict__ VB) {
    __shared__ __align__(16) float smem[5120];   // 20 KB
    int tid = threadIdx.x;
    int bx  = blockIdx.x;

    if (bx < VPREP_BLKS) {
        int i = bx;
        const float4* src = (const float4*)(V + (size_t)i * H_DIM * NBIN);
        uint4* dst = (uint4*)VB + (size_t)i * 2048;
        #pragma unroll
        for (int p = 0; p < 2; ++p) {
            if (p) __syncthreads();
            #pragma unroll
            for (int qv = 0; qv < 5; ++qv) {
                float4 v = src[p * 1280 + qv * 256 + tid];
                *((float4*)&smem[(qv * 256 + tid) * 4]) = v;
            }
            __syncthreads();
            #pragma unroll
            for (int qv = 0; qv < 4; ++qv) {
                int pair = p * 1024 + qv * 256 + tid;
                int kk = pair >> 6, ll = pair & 63;
                int n = ll & 15, hb = kk * 32 + ((ll >> 4) & 3) * 8;
                union { _Float16 hh[8]; uint4 u; } o;
                #pragma unroll
                for (int jj = 0; jj < 8; ++jj)
                    o.hh[jj] = (_Float16)((n < NBIN) ? smem[(hb + jj) * NBIN + n - p * 5120] : 0.0f);
                dst[pair] = o.u;
            }
        }
    } else {
        int qw = bx - VPREP_BLKS;
        int j0 = (qw % 13) * 64, h0 = (qw / 13) * 64;
        float (*t)[65] = (float(*)[65])smem;
        int tj = tid & 63, tr = tid >> 6;
        int j = j0 + tj;
        #pragma unroll
        for (int r = 0; r < 16; ++r) {
            int hh = tr * 16 + r;
            t[hh][tj] = (j < D_DIM) ? W[(size_t)(h0 + hh) * D_DIM + j] : 0.0f;
        }
        __syncthreads();
        #pragma unroll
        for (int r = 0; r < 16; ++r) {
            int jj = tr * 16 + r;
            int jo = j0 + jj;
            if (jo < D_DIM) Wt2h[(size_t)jo * H_DIM + h0 + tj] = (_Float16)(t[tj][jj] * LOG2E);
        }
    }
}

// ---------------------------------------------------------------------------
// k_pscan: coalesced prefix-scan, checkpoint every 8 i's (T_PS=98). (unchanged)
// ---------------------------------------------------------------------------
__global__ __launch_bounds__(256)
void k_pscan(const _Float16* __restrict__ Wt2h, const int* __restrict__ x,
             const float* __restrict__ c, _Float16* __restrict__ PA) {
    int b   = blockIdx.x;
    int hg  = blockIdx.y;
    int tid = threadIdx.x;
    int hcol = hg * 256 + tid;        // uint column 0..511
    int h0   = hcol * 2;

    __shared__ float xs[D_DIM];
    if (tid < D_DIM / 4) {
        int4 xi = ((const int4*)(x + (size_t)b * D_DIM))[tid];
        *((float4*)&xs[tid * 4]) =
            make_float4((float)xi.x, (float)xi.y, (float)xi.z, (float)xi.w);
    }
    float acc0 = c[h0] * LOG2E, acc1 = c[h0 + 1] * LOG2E;
    __syncthreads();

    const uint* wp  = (const uint*)Wt2h;   // [784][512] uints, h-contiguous
    uint*       pau = (uint*)PA;

    uint wvA[8], wvB[8];
    auto ldrow = [&](int t, uint (&wv)[8]) {
        #pragma unroll
        for (int r = 0; r < 8; ++r)
            wv[r] = wp[(size_t)(t * 8 + r) * 512 + hcol];
    };
    auto emit = [&](int t) {
        union { _Float16 hh[2]; uint u; } uu;
        uu.hh[0] = (_Float16)acc0; uu.hh[1] = (_Float16)acc1;
        pau[((size_t)t * B_DIM + b) * 512 + hcol] = uu.u;
    };
    auto fmas = [&](int t, const uint (&wv)[8]) {
        #pragma unroll
        for (int r = 0; r < 8; ++r) {
            union { uint u; _Float16 hh[2]; } uu; uu.u = wv[r];
            float xf = xs[t * 8 + r];
            acc0 += xf * (float)uu.hh[0];
            acc1 += xf * (float)uu.hh[1];
        }
    };

    ldrow(0, wvA);
    for (int t = 0; t < T_PS; t += 2) {       // t = 0,2,...,96
        ldrow(t + 1, wvB);
        emit(t);     fmas(t, wvA);
        if (t + 2 < T_PS) ldrow(t + 2, wvA);
        emit(t + 1); fmas(t + 1, wvB);
    }
}

// ---------------------------------------------------------------------------
// k_main: 512 threads = 2 groups x 4 waves. Group g owns i's [i0+8g, i0+8g+8)
// from its own PA checkpoint. launch_bounds(512,2): 2 blocks/CU -> VGPR cap
// 128 (kernel needs ~100; round 6's (512,4) forced 64 -> 210 MB spill traffic).
// ---------------------------------------------------------------------------
__global__ __launch_bounds__(512, 2)
void k_main(const _Float16* __restrict__ VB, const _Float16* __restrict__ Wt2h,
            const _Float16* __restrict__ PA, const int* __restrict__ x,
            const float* __restrict__ bias, float* __restrict__ out) {
    int bid = blockIdx.x;
    int lb  = (bid & 7) * 98 + (bid >> 3);   // XCD-chunked swizzle (784 = 8*98)
    int tc  = lb >> 4;           // chunk 0..48
    int bt  = lb & 15;           // batch tile 0..15
    int tid = threadIdx.x;
    int g   = tid >> 8;          // i-group 0/1
    int w   = (tid >> 6) & 3;    // wave within group (K-split of H)
    int l   = tid & 63;
    int bl  = l & 15;            // MFMA A row == batch row within tile
    int kg  = l >> 4;            // 0..3
    int bg  = bt * BT + bl;
    int ib  = tc * G_CH;         // block's first i
    int i0  = ib + g * P_CH;     // group's first i

    __shared__ float red[2][4][64][17];      // [group][wave][lane][16+pad] = 34.8 KB
    __shared__ float bs[G_CH][16];           // 1 KB

    {   // stage bias for the block's 16 i's (covered by barrier B1)
        if (tid < 256) {
            int ii = tid >> 4, n = tid & 15;
            bs[ii][n] = (n < NBIN) ? bias[(size_t)(ib + ii) * NBIN + n] : 0.0f;
        }
    }

    // a[8][8] from this group's PA checkpoint (exclusive prefix, log2 domain)
    float a[8][8];
    {
        int ct = tc * 2 + g;     // checkpoint index (stride-8)
        const _Float16* src = PA + ((size_t)ct * B_DIM + bg) * H_DIM + w * 256 + kg * 8;
        #pragma unroll
        for (int m = 0; m < 8; ++m) {
            half8_t av = *((const half8_t*)(src + m * 32));
            #pragma unroll
            for (int j = 0; j < 8; ++j) a[m][j] = (float)av[j];
        }
    }

    const int4* xp = (const int4*)(x + (size_t)bg * D_DIM + i0);

    // VB: 4-slot rolling prefetch over this group's 64 steps (8 ii x 8 m)
    const uint4* vp = (const uint4*)VB + ((size_t)i0 * 32 + w * 8) * 64 + l;
    uint4 vbuf[4];
    vbuf[0] = vp[0];
    vbuf[1] = vp[64];
    const uint4* vpr = vp + 128;             // next refill: step 2

    // Wt2h operand: 2-slot consume-then-refill (distance 2)
    const _Float16* whp = Wt2h + (size_t)i0 * H_DIM + w * 256 + kg * 8;
    half8_t whbuf[2];
    whbuf[0] = *((const half8_t*)whp);
    whbuf[1] = *((const half8_t*)(whp + 32));
    const _Float16* whr = whp + 64;          // next refill: step 2

    float4_t acc = {0.f, 0.f, 0.f, 0.f};

    auto softmax_store = [&](int q) {
        float p4[4];
        #pragma unroll
        for (int qq = 0; qq < 4; ++qq) {
            float tot = red[g][0][l][qq * 4 + w] + red[g][1][l][qq * 4 + w]
                      + red[g][2][l][qq * 4 + w] + red[g][3][l][qq * 4 + w];
            float v = (bl < NBIN) ? tot + bs[g * P_CH + q * 4 + qq][bl] : -3.0e38f;
            float vm = v;
            vm = fmaxf(vm, __shfl_xor(vm, 1));
            vm = fmaxf(vm, __shfl_xor(vm, 2));
            vm = fmaxf(vm, __shfl_xor(vm, 4));
            vm = fmaxf(vm, __shfl_xor(vm, 8));
            float e = __builtin_amdgcn_exp2f((v - vm) * LOG2E);
            float ss = e;
            ss += __shfl_xor(ss, 1); ss += __shfl_xor(ss, 2);
            ss += __shfl_xor(ss, 4); ss += __shfl_xor(ss, 8);
            p4[qq] = e * __builtin_amdgcn_rcpf(ss);
        }
        if (bl < NBIN) {
            int b = bt * BT + kg * 4 + w;    // this thread's C row = batch row
            size_t base = ((size_t)b * NBIN + bl) * D_DIM + i0 + q * 4;
            *((float4*)(out + base)) = make_float4(p4[0], p4[1], p4[2], p4[3]);
        }
    };

    for (int q = 0; q < 2; ++q) {            // two quarters of 4 i's per group
        int4 xi = xp[q];
        float xq0 = (float)xi.x, xq1 = (float)xi.y, xq2 = (float)xi.z, xq3 = (float)xi.w;
        #pragma unroll
        for (int s = 0; s < 32; ++s) {       // all register indices static in s
            const int iis = s >> 3;          // ii within quarter
            const int m   = s & 7;
            const int nn  = q * 32 + s + 2;  // prefetch target (of 64)
            half8_t wh = whbuf[s & 1];       // consume ...
            if (nn < 64) {                   // ... then refill same slot for s+2
                vbuf[(s + 2) & 3] = *vpr;
                whbuf[s & 1] = *((const half8_t*)whr);
                vpr += (((s + 3) & 7) == 0) ? 1600 : 64;   // uint4 stride to nn+1
                whr += (((s + 3) & 7) == 0) ? 800  : 32;   // f16 stride to nn+1
            }
            union { half8_t h8; uint u32[4]; } af;
            #pragma unroll
            for (int p = 0; p < 4; ++p) {
                float s0 = __builtin_amdgcn_rcpf(1.0f + __builtin_amdgcn_exp2f(-a[m][2 * p]));
                float s1 = __builtin_amdgcn_rcpf(1.0f + __builtin_amdgcn_exp2f(-a[m][2 * p + 1]));
                union { fp16x2_t v; uint u; } cv;
                cv.v = __builtin_amdgcn_cvt_pkrtz(s0, s1);
                af.u32[p] = cv.u;
            }
            union { half8_t h8; uint4 u; } bf;
            bf.u = vbuf[s & 3];
            acc = __builtin_amdgcn_mfma_f32_16x16x32_f16(af.h8, bf.h8, acc, 0, 0, 0);
            float xf = (iis == 0) ? xq0 : (iis == 1) ? xq1 : (iis == 2) ? xq2 : xq3;
            a[m][0] += xf * (float)wh[0]; a[m][1] += xf * (float)wh[1];
            a[m][2] += xf * (float)wh[2]; a[m][3] += xf * (float)wh[3];
            a[m][4] += xf * (float)wh[4]; a[m][5] += xf * (float)wh[5];
            a[m][6] += xf * (float)wh[6]; a[m][7] += xf * (float)wh[7];
            if (m == 7) {                    // flush this ii's logits
                float* rp = &red[g][w][l][iis * 4];
                rp[0] = acc[0]; rp[1] = acc[1]; rp[2] = acc[2]; rp[3] = acc[3];
                acc = (float4_t){0.f, 0.f, 0.f, 0.f};
            }
        }
        __syncthreads();                     // red[g] complete (q=0 also covers bs)
        softmax_store(q);
        if (q == 0) __syncthreads();         // all softmax reads done before Q1 flush
    }
}

extern "C" void kernel_launch(void* const* d_in, const int* in_sizes, int n_in,
                              void* d_out, int out_size, void* d_ws, size_t ws_size,
                              hipStream_t stream) {
    const int*   x    = (const int*)d_in[0];
    const float* W    = (const float*)d_in[1];
    const float* c    = (const float*)d_in[2];
    const float* V    = (const float*)d_in[3];
    const float* bias = (const float*)d_in[4];
    float* out = (float*)d_out;

    char* ws = (char*)d_ws;
    size_t off = 0;
    _Float16* Wt2h = (_Float16*)(ws + off);
    off += (size_t)D_DIM * H_DIM * sizeof(_Float16);
    off = (off + 255) & ~(size_t)255;
    _Float16* VB = (_Float16*)(ws + off);
    off += (size_t)D_DIM * 32 * 64 * 8 * sizeof(_Float16);
    off = (off + 255) & ~(size_t)255;
    _Float16* PA = (_Float16*)(ws + off);   // [98][256][1024] f16 = 51.4 MB

    k_prep<<<dim3(VPREP_BLKS + WPREP_BLKS), 256, 0, stream>>>(W, V, Wt2h, VB);
    k_pscan<<<dim3(B_DIM, 2), 256, 0, stream>>>(Wt2h, x, c, PA);
    k_main<<<dim3(D_DIM), 512, 0, stream>>>(VB, Wt2h, PA, x, bias, out);
}